// Round 9
// baseline (8803.338 us; speedup 1.0000x reference)
//
#include <hip/hip_runtime.h>

// ---------------------------------------------------------------------------
// VQ-VAE encoder — numpy-pairwise fp32 emulation (R12 semantics, PASSING).
// R22: BARRIER-FREE, LDS-FREE conv2/conv3. Evidence: R15-R21 all plateau at
// 515-565us regardless of barrier count (8/16/32) and occupancy (34-65%) —
// the LDS-staged barrier-coupled pipeline is the structural limit (~190us
// correlated idle). Fix: every operand loaded per-thread straight from
// global (inputs hit L1 via 16-way cog redundancy; weights L2-resident),
// waves fully independent. Boundaries absorbed by PADDED intermediates:
//   h1c: [img][64][258][264]  (+1 halo, zeros; conv1 writes interior+halo)
//   h2c: [img][128][130][136] (+1 halo; conv2 writes interior+halo)
// so all conv2/conv3 loads are unconditional aligned v2f loads.
// Bit-exactness invariant unchanged: identical products, per-accumulator
// order per ci (+p1, +p2), identical leaf/fold trees. Only operand source
// and address maps changed. conv4/vq unchanged from R12.
// d_out: z_q_st[262144] | loss[1] | idx[65536]
// ---------------------------------------------------------------------------

#define TREE8(r) ((((r)[0]+(r)[1])+((r)[2]+(r)[3]))+((((r)[4]+(r)[5]))+((r)[6]+(r)[7])))

typedef __attribute__((__ext_vector_type__(2))) float v2f;

// layout constants (floats)
#define ROW1   264
#define PLANE1 68112          // 258*264
#define IMG1   4359168u       // 64*PLANE1
#define ROW2   136
#define PLANE2 17680          // 130*136
#define IMG2   2263040u       // 128*PLANE2

// d = {a.lo*w.lo, a.lo*w.hi}  (broadcast low dword of a)
__device__ __forceinline__ v2f pk_mul_lo(v2f a, v2f w) {
    v2f d;
    asm("v_pk_mul_f32 %0, %1, %2 op_sel:[0,0] op_sel_hi:[0,1]"
        : "=v"(d) : "v"(a), "v"(w));
    return d;
}
// d = {a.hi*w.lo, a.hi*w.hi}  (broadcast high dword of a)
__device__ __forceinline__ v2f pk_mul_hi(v2f a, v2f w) {
    v2f d;
    asm("v_pk_mul_f32 %0, %1, %2 op_sel:[1,0] op_sel_hi:[1,1]"
        : "=v"(d) : "v"(a), "v"(w));
    return d;
}
// r += p (per-half IEEE add, in place)
__device__ __forceinline__ void pk_acc(v2f& r, v2f p) {
    asm("v_pk_add_f32 %0, %0, %1" : "+v"(r) : "v"(p));
}
// d = a + b (per-half IEEE add)
__device__ __forceinline__ v2f pk_add2(v2f a, v2f b) {
    v2f d;
    asm("v_pk_add_f32 %0, %1, %2" : "=v"(d) : "v"(a), "v"(b));
    return d;
}

// ---------------- weight transform: wT[ci][f][co] from w[co][ci][f]
__global__ __launch_bounds__(256) void wt_kernel(
    const float* __restrict__ w2, const float* __restrict__ w3,
    float* __restrict__ wT2, float* __restrict__ wT3) {
    int g = blockIdx.x * 256 + threadIdx.x;
    if (g < 131072) {             // conv2: ci 64, f 16, co 128
        int co = g & 127, f = (g >> 7) & 15, ci = g >> 11;
        wT2[g] = w2[co * 1024 + ci * 16 + f];
    }
    int g2 = g - 131072;
    if (g2 >= 0 && g2 < 262144) { // conv3: ci 128, f 16, co 128
        int co = g2 & 127, f = (g2 >> 7) & 15, ci = g2 >> 11;
        wT3[g2] = w3[co * 2048 + ci * 16 + f];
    }
}

// ---------------- conv1: 1->64, 4x4, s2, p1. Writes PADDED h1c (+halo 0s).
__global__ __launch_bounds__(256) void conv1_kernel(
    const float* __restrict__ x, const float* __restrict__ w1,
    const float* __restrict__ b1, float* __restrict__ h1) {
#pragma clang fp contract(off)
    __shared__ __align__(16) float wl[64 * 16];
    __shared__ float bl[64];
    const int tid = threadIdx.x;
    {
        const float4* src = (const float4*)w1;
        ((float4*)wl)[tid] = src[tid];
        if (tid < 64) bl[tid] = b1[tid];
    }
    __syncthreads();

    const int oxl = tid & 63, oyq = tid >> 6;
    const int img = blockIdx.z;
    const int ox  = blockIdx.x * 64 + oxl;
    const int oy0 = blockIdx.y * 16 + oyq * 4;
    const float* xi = x + (size_t)img * 262144;

    float in[10][4];
    const int ix0 = 2 * ox - 1;
    const int iy0 = 2 * oy0 - 1;
#pragma unroll
    for (int r = 0; r < 10; ++r) {
        int iy = iy0 + r;
#pragma unroll
        for (int k = 0; k < 4; ++k) {
            int ixx = ix0 + k;
            bool ok = ((unsigned)iy < 512u) && ((unsigned)ixx < 512u);
            in[r][k] = ok ? xi[iy * 512 + ixx] : 0.f;
        }
    }

    float* outp = h1 + (size_t)img * IMG1;
#pragma unroll
    for (int c = 0; c < 64; ++c) {
        const float* wp = &wl[c * 16];
        float bv = bl[c];
#pragma unroll
        for (int p = 0; p < 4; ++p) {
            float a[16];
#pragma unroll
            for (int f = 0; f < 16; ++f)
                a[f] = in[2 * p + (f >> 2)][f & 3] * wp[f];
            float r[8];
#pragma unroll
            for (int j = 0; j < 8; ++j) r[j] = a[j] + a[8 + j];
            float tot = TREE8(r);
            const int row = oy0 + p;
            size_t ro = (size_t)c * PLANE1 + (size_t)(row + 1) * ROW1;
            outp[ro + ox + 1] = fmaxf(tot + bv, 0.f);
            // halo zeros (persist across batches; interior rewritten)
            if (ox == 0)   outp[ro] = 0.f;
            if (ox == 255) outp[ro + 257] = 0.f;
            if (row == 0) {
                size_t r0 = (size_t)c * PLANE1;
                outp[r0 + ox + 1] = 0.f;
                if (ox == 0)   outp[r0] = 0.f;
                if (ox == 255) outp[r0 + 257] = 0.f;
            }
            if (row == 255) {
                size_t r2 = (size_t)c * PLANE1 + (size_t)257 * ROW1;
                outp[r2 + ox + 1] = 0.f;
                if (ox == 0)   outp[r2] = 0.f;
                if (ox == 255) outp[r2 + 257] = 0.f;
            }
        }
    }
}

// ---------------- conv2: 64->128, 4x4, s2, p1. Barrier-free, zero LDS.
// Padded input h1c; padded output h2c (+halo zeros from epilogue).
__global__ __launch_bounds__(256) void conv2_kernel(
    const float* __restrict__ in, const float* __restrict__ wT,
    const float* __restrict__ bias, float* __restrict__ out) {
#pragma clang fp contract(off)
    const int tid = threadIdx.x;
    const int xg = tid & 15, cog = tid >> 4;
    const int cog2 = cog * 2;
    const int xt = blockIdx.x & 3, cot = blockIdx.x >> 2;
    const int oy = blockIdx.y;
    const int img = blockIdx.z;
    const int xbase = 32 * xt;

    // padded coords: row = 2*oy + ky  (iy+1), col = 2*xbase + 4*xg + k (gx+1)
    const float* ib0 = in + (size_t)img * IMG1
                       + (size_t)(2 * oy) * ROW1 + (2 * xbase + 4 * xg);
    const float* wb0 = wT + cot * 32 + cog2;

    v2f r[8][2];
    v2f tA[2], tB[2], Q0[2], TOT[2];
#pragma unroll
    for (int j = 0; j < 8; ++j)
#pragma unroll
        for (int xi2 = 0; xi2 < 2; ++xi2) r[j][xi2] = (v2f){0.f, 0.f};

    for (int L = 0; L < 8; ++L) {               // 8 leaves x 8 ci = K 1024
        const float* ibL = ib0 + (size_t)(8 * L) * PLANE1;
        const float* wbL = wb0 + (size_t)(8 * L) * 2048;
#pragma unroll
        for (int cl = 0; cl < 8; ++cl) {
            const float* ib = ibL + cl * PLANE1;
            const float* wq = wbL + cl * 2048;
            v2f rp[4][3], wp[16];
#pragma unroll
            for (int ky = 0; ky < 4; ++ky) {
                const float* rw = ib + ky * ROW1;
                rp[ky][0] = *(const v2f*)(rw);
                rp[ky][1] = *(const v2f*)(rw + 2);
                rp[ky][2] = *(const v2f*)(rw + 4);
            }
#pragma unroll
            for (int f = 0; f < 16; ++f)
                wp[f] = *(const v2f*)(wq + f * 128);
#pragma unroll
            for (int j = 0; j < 8; ++j) {
                const int ky1 = j >> 2, kx1 = j & 3;
#pragma unroll
                for (int xi2 = 0; xi2 < 2; ++xi2) {
                    const int e = 2 * xi2 + kx1;       // 0..5
                    v2f p1 = (e & 1) ? pk_mul_hi(rp[ky1][e >> 1], wp[j])
                                     : pk_mul_lo(rp[ky1][e >> 1], wp[j]);
                    pk_acc(r[j][xi2], p1);
                    v2f p2 = (e & 1) ? pk_mul_hi(rp[2 + ky1][e >> 1], wp[j + 8])
                                     : pk_mul_lo(rp[2 + ky1][e >> 1], wp[j + 8]);
                    pk_acc(r[j][xi2], p2);
                }
            }
        }
        // leaf fold (EXACT tree: ((l0+l1)+(l2+l3))+((l4+l5)+(l6+l7)))
#pragma unroll
        for (int xi2 = 0; xi2 < 2; ++xi2) {
            v2f t01 = pk_add2(r[0][xi2], r[1][xi2]);
            v2f t23 = pk_add2(r[2][xi2], r[3][xi2]);
            v2f t45 = pk_add2(r[4][xi2], r[5][xi2]);
            v2f t67 = pk_add2(r[6][xi2], r[7][xi2]);
            v2f lf = pk_add2(pk_add2(t01, t23), pk_add2(t45, t67));
            const int m = L & 3;
            if (m == 0) tA[xi2] = lf;
            else if (m == 1) tA[xi2] = pk_add2(tA[xi2], lf);
            else if (m == 2) tB[xi2] = lf;
            else {
                tB[xi2] = pk_add2(tB[xi2], lf);
                v2f q = pk_add2(tA[xi2], tB[xi2]);
                if (L == 3) Q0[xi2] = q;
                else        TOT[xi2] = pk_add2(Q0[xi2], q);
            }
        }
#pragma unroll
        for (int j = 0; j < 8; ++j)
#pragma unroll
            for (int xi2 = 0; xi2 < 2; ++xi2) r[j][xi2] = (v2f){0.f, 0.f};
    }

    {
        v2f bvp = *(const v2f*)(bias + cot * 32 + cog2);
        v2f T0 = pk_add2(TOT[0], bvp);
        v2f T1 = pk_add2(TOT[1], bvp);
        const int co0 = cot * 32 + cog2;
        float r00 = fmaxf(T0.x, 0.f), r01 = fmaxf(T1.x, 0.f);
        float r10 = fmaxf(T0.y, 0.f), r11 = fmaxf(T1.y, 0.f);
        float* op = out + (size_t)img * IMG2;
        const int colp = xbase + 2 * xg + 1;          // padded col (1..128)
        float* p0 = op + (size_t)co0 * PLANE2 + (size_t)(oy + 1) * ROW2 + colp;
        float* p1p = p0 + PLANE2;
        p0[0] = r00; p0[1] = r01;
        p1p[0] = r10; p1p[1] = r11;
        // halo zeros for this co pair (cols 0/129, rows 0/129)
        if (xt == 0 && xg == 0) { p0[-1] = 0.f; p1p[-1] = 0.f; }
        if (xt == 3 && xg == 15) { p0[2] = 0.f; p1p[2] = 0.f; }
        if (oy == 0) {
            float* q0 = p0 - ROW2; float* q1 = p1p - ROW2;
            q0[0] = 0.f; q0[1] = 0.f; q1[0] = 0.f; q1[1] = 0.f;
            if (xt == 0 && xg == 0) { q0[-1] = 0.f; q1[-1] = 0.f; }
            if (xt == 3 && xg == 15) { q0[2] = 0.f; q1[2] = 0.f; }
        }
        if (oy == 127) {
            float* q0 = p0 + ROW2; float* q1 = p1p + ROW2;
            q0[0] = 0.f; q0[1] = 0.f; q1[0] = 0.f; q1[1] = 0.f;
            if (xt == 0 && xg == 0) { q0[-1] = 0.f; q1[-1] = 0.f; }
            if (xt == 3 && xg == 15) { q0[2] = 0.f; q1[2] = 0.f; }
        }
    }
}

// ---------------- conv3: 128->128, 4x4, s2, p1. Barrier-free, zero LDS.
// Padded input h2c; output h3c layout UNCHANGED (conv4 reads it as before).
__global__ __launch_bounds__(256) void conv3_kernel(
    const float* __restrict__ in, const float* __restrict__ wT,
    const float* __restrict__ bias, float* __restrict__ out) {
#pragma clang fp contract(off)
    const int tid = threadIdx.x;
    const int xg = tid & 15, cog = tid >> 4;
    const int cog2 = cog * 2;
    const int xt = blockIdx.x & 1, cot = blockIdx.x >> 1;
    const int oy = blockIdx.y;
    const int img = blockIdx.z;
    const int xbase = 32 * xt;

    const float* ib0 = in + (size_t)img * IMG2
                       + (size_t)(2 * oy) * ROW2 + (2 * xbase + 4 * xg);
    const float* wb0 = wT + cot * 32 + cog2;

    v2f r[8][2];
    v2f tA[2], tB[2], Q0[2], AB0[2], TOT[2];
#pragma unroll
    for (int j = 0; j < 8; ++j)
#pragma unroll
        for (int xi2 = 0; xi2 < 2; ++xi2) r[j][xi2] = (v2f){0.f, 0.f};

    for (int L = 0; L < 16; ++L) {              // 16 leaves x 8 ci = K 2048
        const float* ibL = ib0 + (size_t)(8 * L) * PLANE2;
        const float* wbL = wb0 + (size_t)(8 * L) * 2048;
#pragma unroll
        for (int cl = 0; cl < 8; ++cl) {
            const float* ib = ibL + cl * PLANE2;
            const float* wq = wbL + cl * 2048;
            v2f rp[4][3], wp[16];
#pragma unroll
            for (int ky = 0; ky < 4; ++ky) {
                const float* rw = ib + ky * ROW2;
                rp[ky][0] = *(const v2f*)(rw);
                rp[ky][1] = *(const v2f*)(rw + 2);
                rp[ky][2] = *(const v2f*)(rw + 4);
            }
#pragma unroll
            for (int f = 0; f < 16; ++f)
                wp[f] = *(const v2f*)(wq + f * 128);
#pragma unroll
            for (int j = 0; j < 8; ++j) {
                const int ky1 = j >> 2, kx1 = j & 3;
#pragma unroll
                for (int xi2 = 0; xi2 < 2; ++xi2) {
                    const int e = 2 * xi2 + kx1;
                    v2f p1 = (e & 1) ? pk_mul_hi(rp[ky1][e >> 1], wp[j])
                                     : pk_mul_lo(rp[ky1][e >> 1], wp[j]);
                    pk_acc(r[j][xi2], p1);
                    v2f p2 = (e & 1) ? pk_mul_hi(rp[2 + ky1][e >> 1], wp[j + 8])
                                     : pk_mul_lo(rp[2 + ky1][e >> 1], wp[j + 8]);
                    pk_acc(r[j][xi2], p2);
                }
            }
        }
        // per-leaf fold; EXACT per-half tree, then AB0 + AB1
#pragma unroll
        for (int xi2 = 0; xi2 < 2; ++xi2) {
            v2f t01 = pk_add2(r[0][xi2], r[1][xi2]);
            v2f t23 = pk_add2(r[2][xi2], r[3][xi2]);
            v2f t45 = pk_add2(r[4][xi2], r[5][xi2]);
            v2f t67 = pk_add2(r[6][xi2], r[7][xi2]);
            v2f lf = pk_add2(pk_add2(t01, t23), pk_add2(t45, t67));
            const int L8 = L & 7, half = L >> 3;
            const int m = L8 & 3;
            if (m == 0) tA[xi2] = lf;
            else if (m == 1) tA[xi2] = pk_add2(tA[xi2], lf);
            else if (m == 2) tB[xi2] = lf;
            else {
                tB[xi2] = pk_add2(tB[xi2], lf);
                v2f q = pk_add2(tA[xi2], tB[xi2]);
                if (L8 == 3) Q0[xi2] = q;
                else {
                    v2f h = pk_add2(Q0[xi2], q);   // this half's p(1024)
                    if (half == 0) AB0[xi2] = h;
                    else           TOT[xi2] = pk_add2(AB0[xi2], h); // p(2048)
                }
            }
        }
#pragma unroll
        for (int j = 0; j < 8; ++j)
#pragma unroll
            for (int xi2 = 0; xi2 < 2; ++xi2) r[j][xi2] = (v2f){0.f, 0.f};
    }

    {
        v2f bvp = *(const v2f*)(bias + cot * 32 + cog2);
        v2f T0 = pk_add2(TOT[0], bvp);
        v2f T1 = pk_add2(TOT[1], bvp);
        const int co0 = cot * 32 + cog2;
        float r00 = fmaxf(T0.x, 0.f), r01 = fmaxf(T1.x, 0.f);
        float r10 = fmaxf(T0.y, 0.f), r11 = fmaxf(T1.y, 0.f);
        v2f o0; o0.x = r00; o0.y = r01;
        v2f o1; o1.x = r10; o1.y = r11;
        size_t base = (size_t)img * 524288 + (size_t)oy * 64 + xbase + 2 * xg;
        *(v2f*)&out[base + (size_t)co0 * 4096] = o0;
        *(v2f*)&out[base + (size_t)(co0 + 1) * 4096] = o1;
    }
}

// ---------------- conv4: 128->4, 3x3, s1, p1 (unchanged from R12)
__global__ __launch_bounds__(256) void conv4_kernel(
    const float* __restrict__ h3, const float* __restrict__ w4,
    const float* __restrict__ b4, float* __restrict__ z, int b0) {
#pragma clang fp contract(off)
    __shared__ __align__(16) float Il3[8][3][66];
    __shared__ __align__(16) float w4l[4608];
    const int tid = threadIdx.x;
    const int wl = tid & 63, co = tid >> 6;
    const int h = blockIdx.x, bl = blockIdx.y;
    const float* inp = h3 + (size_t)bl * 524288;

    for (int it = 0; it < 18; ++it) {
        int e = tid + it * 256;
        if (e < 4608) w4l[e] = w4[e];
    }

    float ls[16];
    for (int L = 0; L < 16; ++L) {
        __syncthreads();
        for (int it = 0; it < 7; ++it) {
            int e = tid + it * 256;
            if (e < 1584) {
                int cil = e / 198;
                int rem = e - cil * 198;
                int ky = rem / 66, col = rem - ky * 66;
                int iy = h - 1 + ky, gx = col - 1;
                bool ok = ((unsigned)iy < 64u) && ((unsigned)gx < 64u);
                Il3[cil][ky][col] =
                    ok ? inp[(size_t)(8 * L + cil) * 4096 + iy * 64 + gx] : 0.f;
            }
        }
        __syncthreads();

        float r[8];
#pragma unroll
        for (int j = 0; j < 8; ++j) r[j] = 0.f;
#pragma unroll
        for (int i = 0; i < 9; ++i) {
#pragma unroll
            for (int j = 0; j < 8; ++j) {
                int kk = 8 * i + j;
                int cil = kk / 9, f = kk - 9 * cil;
                int ky = f / 3, kx = f - 3 * ky;
                float p = Il3[cil][ky][wl + kx] *
                          w4l[co * 1152 + (8 * L + cil) * 9 + f];
                r[j] = r[j] + p;
            }
        }
        float t01 = r[0] + r[1], t23 = r[2] + r[3];
        float t45 = r[4] + r[5], t67 = r[6] + r[7];
        ls[L] = (t01 + t23) + (t45 + t67);
    }

    float a01 = ls[0] + ls[1],  a23 = ls[2] + ls[3];
    float a45 = ls[4] + ls[5],  a67 = ls[6] + ls[7];
    float A = (a01 + a23) + (a45 + a67);
    float c01 = ls[8] + ls[9],  c23 = ls[10] + ls[11];
    float c45 = ls[12] + ls[13], c67 = ls[14] + ls[15];
    float B = (c01 + c23) + (c45 + c67);
    float tot = A + B;

    z[(size_t)(b0 + bl) * 16384 + (size_t)co * 4096 + (size_t)h * 64 + wl] =
        tot + b4[co];
}

// ---------------- VQ (unchanged from R12)
__global__ __launch_bounds__(256) void vq_kernel(
    const float* __restrict__ z, const float* __restrict__ emb,
    float* __restrict__ zq_out, float* __restrict__ idx_out,
    float* __restrict__ loss_out) {
#pragma clang fp contract(off)
    __shared__ float4 el[512];
    __shared__ float t3s[512];
    const int tid = threadIdx.x;
#pragma unroll
    for (int i = 0; i < 2; ++i) {
        int e = tid + i * 256;
        float4 v = ((const float4*)emb)[e];
        el[e] = v;
        float q0 = v.x * v.x, q1 = v.y * v.y, q2 = v.z * v.z, q3 = v.w * v.w;
        t3s[e] = ((q0 + q1) + q2) + q3;
    }
    __syncthreads();

    const int r = blockIdx.x * 256 + tid;
    float4 v = ((const float4*)z)[r];
    float q0 = v.x * v.x, q1 = v.y * v.y, q2 = v.z * v.z, q3 = v.w * v.w;
    float t1 = ((q0 + q1) + q2) + q3;

    float best = __builtin_inff();
    int bi = 0;
    for (int jj = 0; jj < 512; ++jj) {
        float4 e = el[jj];
        float t2 = fmaf(v.x, e.x, 0.f);
        t2 = fmaf(v.y, e.y, t2);
        t2 = fmaf(v.z, e.z, t2);
        t2 = fmaf(v.w, e.w, t2);
        float two_t2 = 2.f * t2;
        float d = (t1 - two_t2) + t3s[jj];
        if (d < best) { best = d; bi = jj; }
    }
    float4 q = el[bi];
    ((float4*)zq_out)[r] = q;
    idx_out[r] = (float)bi;

    double dx = (double)q.x - v.x, dy = (double)q.y - v.y;
    double dz2 = (double)q.z - v.z, dw = (double)q.w - v.w;
    double part = dx * dx + dy * dy + dz2 * dz2 + dw * dw;
#pragma unroll
    for (int off = 32; off > 0; off >>= 1) part += __shfl_down(part, off, 64);
    __shared__ double ps[4];
    if ((tid & 63) == 0) ps[tid >> 6] = part;
    __syncthreads();
    if (tid == 0) {
        double s = ps[0] + ps[1] + ps[2] + ps[3];
        atomicAdd(loss_out, (float)(s * (1.25 / 262144.0)));
    }
}

// ---------------------------------------------------------------------------
extern "C" void kernel_launch(void* const* d_in, const int* in_sizes, int n_in,
                              void* d_out, int out_size, void* d_ws, size_t ws_size,
                              hipStream_t stream) {
    const float* x   = (const float*)d_in[0];
    const float* w1  = (const float*)d_in[1];
    const float* b1  = (const float*)d_in[2];
    const float* w2  = (const float*)d_in[3];
    const float* b2  = (const float*)d_in[4];
    const float* w3  = (const float*)d_in[5];
    const float* b3  = (const float*)d_in[6];
    const float* w4  = (const float*)d_in[7];
    const float* b4  = (const float*)d_in[8];
    const float* emb = (const float*)d_in[9];
    float* out = (float*)d_out;

    float* ws = (float*)d_ws;
    // layout (floats): zb[262144] | wT2[131072] | wT3[262144]
    //   | h1c[CH*4359168 padded] | h2c[CH*2263040 padded] | h3c[CH*524288]
    int CH = 4;
    while (CH > 1 &&
           ((size_t)655360u + (size_t)CH * 7146496u) * 4ull > ws_size)
        CH >>= 1;
    float* zb  = ws;
    float* wT2 = ws + 262144;
    float* wT3 = wT2 + 131072;
    float* h1c = wT3 + 262144;
    float* h2c = h1c + (size_t)CH * 4359168;
    float* h3c = h2c + (size_t)CH * 2263040;

    wt_kernel<<<1536, 256, 0, stream>>>(w2, w3, wT2, wT3);

    for (int b0 = 0; b0 < 16; b0 += CH) {
        conv1_kernel<<<dim3(4, 16, CH), 256, 0, stream>>>(
            x + (size_t)b0 * 262144, w1, b1, h1c);
        conv2_kernel<<<dim3(16, 128, CH), 256, 0, stream>>>(h1c, wT2, b2, h2c);
        conv3_kernel<<<dim3(8, 64, CH), 256, 0, stream>>>(h2c, wT3, b3, h3c);
        conv4_kernel<<<dim3(64, CH), 256, 0, stream>>>(h3c, w4, b4, zb, b0);
    }

    hipMemsetAsync(out + 262144, 0, sizeof(float), stream);  // loss accumulator
    vq_kernel<<<256, 256, 0, stream>>>(zb, emb, out, out + 262144 + 1, out + 262144);
}

// Round 10
// 2939.790 us; speedup vs baseline: 2.9945x; 2.9945x over previous
//
#include <hip/hip_runtime.h>

// ---------------------------------------------------------------------------
// VQ-VAE encoder — numpy-pairwise fp32 emulation (R12 semantics, PASSING).
// R23: per-THREAD 2-oy pairing in conv2/conv3 (base = R20, best verified).
// Diagnosis: R15-R21 plateau (515-565us, invariant to occupancy/barriers) =
// per-CU LDS-pipe bound: 28 ds_read_b64 per cl per wave. R22 (global-direct)
// refuted: VMEM-issue bound, 2.8x worse. Fix: each thread computes oy=2by
// AND oy=2by+1 from one 6-row Il window -> 34 LDS reads per 128 MAC instrs
// (vs 28 per 64): total LDS instructions x0.61, weight reads + barriers per
// output halved. Register reuse keeps peak ~150: rpa holds rows0-1 then
// rows4-5; rpb rows2-3; wp[8] reloaded f0-7 -> f8-15.
// Bit-exactness: per-accumulator order per output unchanged (+p1(cl),
// +p2(cl), ...); identical products; identical fold trees. Only the
// thread->output map changes. conv1/conv4/vq/wt unchanged from R12/R20.
// d_out: z_q_st[262144] | loss[1] | idx[65536]
// ---------------------------------------------------------------------------

#define TREE8(r) ((((r)[0]+(r)[1])+((r)[2]+(r)[3]))+((((r)[4]+(r)[5]))+((r)[6]+(r)[7])))

typedef __attribute__((__ext_vector_type__(2))) float v2f;

// d = {a.lo*w.lo, a.lo*w.hi}  (broadcast low dword of a)
__device__ __forceinline__ v2f pk_mul_lo(v2f a, v2f w) {
    v2f d;
    asm("v_pk_mul_f32 %0, %1, %2 op_sel:[0,0] op_sel_hi:[0,1]"
        : "=v"(d) : "v"(a), "v"(w));
    return d;
}
// d = {a.hi*w.lo, a.hi*w.hi}  (broadcast high dword of a)
__device__ __forceinline__ v2f pk_mul_hi(v2f a, v2f w) {
    v2f d;
    asm("v_pk_mul_f32 %0, %1, %2 op_sel:[1,0] op_sel_hi:[1,1]"
        : "=v"(d) : "v"(a), "v"(w));
    return d;
}
// r += p (per-half IEEE add, in place)
__device__ __forceinline__ void pk_acc(v2f& r, v2f p) {
    asm("v_pk_add_f32 %0, %0, %1" : "+v"(r) : "v"(p));
}
// d = a + b (per-half IEEE add)
__device__ __forceinline__ v2f pk_add2(v2f a, v2f b) {
    v2f d;
    asm("v_pk_add_f32 %0, %1, %2" : "=v"(d) : "v"(a), "v"(b));
    return d;
}

// async global->LDS for one 4-ci weight chunk: 2048 floats, 8 chunks of 256.
// wave w issues chunks w*2..w*2+1; lane l covers floats 4l..4l+3 of chunk.
__device__ __forceinline__ void stage_w4(const float* __restrict__ src0,
                                         float* dst0, int wid, int lane) {
#pragma unroll
    for (int it = 0; it < 2; ++it) {
        int j = wid * 2 + it;
        int e = j * 256 + lane * 4;
        int co = e & 31, f = (e >> 5) & 15, cl = e >> 9;
        const float* src = src0 + cl * 2048 + f * 128 + co;
        __builtin_amdgcn_global_load_lds(
            (const __attribute__((address_space(1))) void*)src,
            (__attribute__((address_space(3))) void*)(dst0 + j * 256),
            16, 0, 0);
    }
}

// one MAC group: 8 j x 2 xi, products rp[ky1][..] * wp[j]  (32 mul + 32 acc)
#define MACGRP(ACC, RP, WP)                                                  \
    {                                                                        \
        _Pragma("unroll") for (int j = 0; j < 8; ++j) {                      \
            const int ky1_ = j >> 2, kx1_ = j & 3;                           \
            _Pragma("unroll") for (int xi = 0; xi < 2; ++xi) {               \
                const int e_ = 2 * xi + kx1_;                                \
                v2f p_ = (e_ & 1) ? pk_mul_hi(RP[ky1_][e_ >> 1], WP[j])      \
                                  : pk_mul_lo(RP[ky1_][e_ >> 1], WP[j]);     \
                pk_acc(ACC[j][xi], p_);                                      \
            }                                                                \
        }                                                                    \
    }

// ---------------- weight transform: wT[ci][f][co] from w[co][ci][f]
__global__ __launch_bounds__(256) void wt_kernel(
    const float* __restrict__ w2, const float* __restrict__ w3,
    float* __restrict__ wT2, float* __restrict__ wT3) {
    int g = blockIdx.x * 256 + threadIdx.x;
    if (g < 131072) {             // conv2: ci 64, f 16, co 128
        int co = g & 127, f = (g >> 7) & 15, ci = g >> 11;
        wT2[g] = w2[co * 1024 + ci * 16 + f];
    }
    int g2 = g - 131072;
    if (g2 >= 0 && g2 < 262144) { // conv3: ci 128, f 16, co 128
        int co = g2 & 127, f = (g2 >> 7) & 15, ci = g2 >> 11;
        wT3[g2] = w3[co * 2048 + ci * 16 + f];
    }
}

// ---------------- conv1: 1->64, 4x4, s2, p1 (unchanged from R12)
__global__ __launch_bounds__(256) void conv1_kernel(
    const float* __restrict__ x, const float* __restrict__ w1,
    const float* __restrict__ b1, float* __restrict__ h1) {
#pragma clang fp contract(off)
    __shared__ __align__(16) float wl[64 * 16];
    __shared__ float bl[64];
    const int tid = threadIdx.x;
    {
        const float4* src = (const float4*)w1;
        ((float4*)wl)[tid] = src[tid];
        if (tid < 64) bl[tid] = b1[tid];
    }
    __syncthreads();

    const int oxl = tid & 63, oyq = tid >> 6;
    const int img = blockIdx.z;
    const int ox  = blockIdx.x * 64 + oxl;
    const int oy0 = blockIdx.y * 16 + oyq * 4;
    const float* xi = x + (size_t)img * 262144;

    float in[10][4];
    const int ix0 = 2 * ox - 1;
    const int iy0 = 2 * oy0 - 1;
#pragma unroll
    for (int r = 0; r < 10; ++r) {
        int iy = iy0 + r;
#pragma unroll
        for (int k = 0; k < 4; ++k) {
            int ixx = ix0 + k;
            bool ok = ((unsigned)iy < 512u) && ((unsigned)ixx < 512u);
            in[r][k] = ok ? xi[iy * 512 + ixx] : 0.f;
        }
    }

    float* outp = h1 + (size_t)img * 4194304;
#pragma unroll
    for (int c = 0; c < 64; ++c) {
        const float* wp = &wl[c * 16];
        float bv = bl[c];
#pragma unroll
        for (int p = 0; p < 4; ++p) {
            float a[16];
#pragma unroll
            for (int f = 0; f < 16; ++f)
                a[f] = in[2 * p + (f >> 2)][f & 3] * wp[f];
            float r[8];
#pragma unroll
            for (int j = 0; j < 8; ++j) r[j] = a[j] + a[8 + j];
            float tot = TREE8(r);
            outp[(size_t)c * 65536 + (size_t)(oy0 + p) * 256 + ox] =
                fmaxf(tot + bv, 0.f);
        }
    }
}

// ---------------- conv2: 64->128, 4x4, s2, p1, 256->128. K=1024.
// 2 oy per THREAD (6-row shared Il window); 16 chunks of 4 ci; chunk-pair
// leaves; 29440B LDS; implicit bounds (R20 lesson).
__global__ __launch_bounds__(256) void conv2_kernel(
    const float* __restrict__ in, const float* __restrict__ wT,
    const float* __restrict__ bias, float* __restrict__ out) {
#pragma clang fp contract(off)
    __shared__ __align__(16) float Wl[2][4][16][32];  // [buf][cl][f][co] 16KB
    __shared__ __align__(16) float Il[2][4][6][68];   // [buf][cl][row][col] 13KB
    const int tid = threadIdx.x;
    const int xg = tid & 15, cog = tid >> 4;
    const int cog2 = cog * 2;
    const int xt = blockIdx.x & 3, cot = blockIdx.x >> 2;
    const int by = blockIdx.y;                 // oy pair: 2*by, 2*by+1
    const int img = blockIdx.z;
    const int xbase = 32 * xt;
    const float* inp = in + (size_t)img * 4194304;
    const int gx0 = 2 * xbase - 1;
    const int iy0 = 4 * by - 1;                // 6 input rows iy0..iy0+5
    const int lane = tid & 63, wid = tid >> 6;

    // staging descriptors: chunk = 4 ci * 6 rows * 66 cols = 1584 floats
    int ldsoff[7]; int goff[7]; bool gok[7];
#pragma unroll
    for (int i = 0; i < 7; ++i) {
        int e = tid + i * 256;
        int cl = e / 396;
        int rem = e - cl * 396;
        int row = rem / 66, col = rem - row * 66;
        int iy = iy0 + row, gx = gx0 + col;
        gok[i] = (e < 1584) && ((unsigned)iy < 256u) && ((unsigned)gx < 256u);
        ldsoff[i] = (cl * 6 + row) * 68 + col;
        goff[i] = cl * 65536 + iy * 256 + gx;
    }
    const float* wbase = wT + cot * 32;

    float rIl[7];
    auto LOAD_IL = [&](int c) {
        const float* p = inp + (size_t)c * 262144;  // 4ci * 65536
#pragma unroll
        for (int i = 0; i < 7; ++i)
            rIl[i] = gok[i] ? p[goff[i]] : 0.f;
    };
    auto WRITE_IL = [&](float* dst) {
#pragma unroll
        for (int i = 0; i < 6; ++i) dst[ldsoff[i]] = rIl[i];
        if (tid < 48) dst[ldsoff[6]] = rIl[6];
    };

    v2f acc[2][8][2];   // [oy][j][xi]
    v2f tA[2][2], tB[2][2], Q0[2][2], TOT[2][2];   // [oy][xi]
#pragma unroll
    for (int o = 0; o < 2; ++o)
#pragma unroll
        for (int j = 0; j < 8; ++j)
#pragma unroll
            for (int xi = 0; xi < 2; ++xi) acc[o][j][xi] = (v2f){0.f, 0.f};

    stage_w4(wbase, &Wl[0][0][0][0], wid, lane);
    LOAD_IL(0);
    WRITE_IL(&Il[0][0][0][0]);
    LOAD_IL(1);
    __syncthreads();

    int buf = 0;
    for (int c = 0; c < 16; ++c) {
        const float* IlC = &Il[buf][0][0][0];
        const float* WlC = &Wl[buf][0][0][0];
        if (c < 15) {
            WRITE_IL(&Il[buf ^ 1][0][0][0]);
            stage_w4(wbase + (size_t)(c + 1) * 8192, &Wl[buf ^ 1][0][0][0],
                     wid, lane);
        }
        if (c < 14) LOAD_IL(c + 2);

        for (int cl = 0; cl < 4; ++cl) {
            v2f rpa[2][3], rpb[2][3], wp[8];
            // rows 0-1 -> rpa, rows 2-3 -> rpb
#pragma unroll
            for (int ky = 0; ky < 2; ++ky) {
                const float* r0 = IlC + (cl * 6 + ky) * 68 + 4 * xg;
                rpa[ky][0] = *(const v2f*)(r0);
                rpa[ky][1] = *(const v2f*)(r0 + 2);
                rpa[ky][2] = *(const v2f*)(r0 + 4);
                const float* r2 = IlC + (cl * 6 + 2 + ky) * 68 + 4 * xg;
                rpb[ky][0] = *(const v2f*)(r2);
                rpb[ky][1] = *(const v2f*)(r2 + 2);
                rpb[ky][2] = *(const v2f*)(r2 + 4);
            }
#pragma unroll
            for (int f = 0; f < 8; ++f)
                wp[f] = *(const v2f*)(WlC + (cl * 16 + f) * 32 + cog2);
            MACGRP(acc[0], rpa, wp);   // oyA +p1(cl): rows 0-1, f 0..7
            MACGRP(acc[1], rpb, wp);   // oyB +p1(cl): rows 2-3, f 0..7
            // reload: wp <- f 8..15, rpa <- rows 4-5
#pragma unroll
            for (int f = 0; f < 8; ++f)
                wp[f] = *(const v2f*)(WlC + (cl * 16 + 8 + f) * 32 + cog2);
#pragma unroll
            for (int ky = 0; ky < 2; ++ky) {
                const float* r4 = IlC + (cl * 6 + 4 + ky) * 68 + 4 * xg;
                rpa[ky][0] = *(const v2f*)(r4);
                rpa[ky][1] = *(const v2f*)(r4 + 2);
                rpa[ky][2] = *(const v2f*)(r4 + 4);
            }
            MACGRP(acc[0], rpb, wp);   // oyA +p2(cl): rows 2-3, f 8..15
            MACGRP(acc[1], rpa, wp);   // oyB +p2(cl): rows 4-5, f 8..15
        }

        // fold after every chunk PAIR (= one 8-ci leaf, EXACT same tree)
        if (c & 1) {
            const int L = c >> 1;
#pragma unroll
            for (int o = 0; o < 2; ++o)
#pragma unroll
                for (int xi = 0; xi < 2; ++xi) {
                    v2f t01 = pk_add2(acc[o][0][xi], acc[o][1][xi]);
                    v2f t23 = pk_add2(acc[o][2][xi], acc[o][3][xi]);
                    v2f t45 = pk_add2(acc[o][4][xi], acc[o][5][xi]);
                    v2f t67 = pk_add2(acc[o][6][xi], acc[o][7][xi]);
                    v2f lf = pk_add2(pk_add2(t01, t23), pk_add2(t45, t67));
                    const int m = L & 3;
                    if (m == 0) tA[o][xi] = lf;
                    else if (m == 1) tA[o][xi] = pk_add2(tA[o][xi], lf);
                    else if (m == 2) tB[o][xi] = lf;
                    else {
                        tB[o][xi] = pk_add2(tB[o][xi], lf);
                        v2f q = pk_add2(tA[o][xi], tB[o][xi]);
                        if (L == 3) Q0[o][xi] = q;
                        else        TOT[o][xi] = pk_add2(Q0[o][xi], q);
                    }
                }
#pragma unroll
            for (int o = 0; o < 2; ++o)
#pragma unroll
                for (int j = 0; j < 8; ++j)
#pragma unroll
                    for (int xi = 0; xi < 2; ++xi)
                        acc[o][j][xi] = (v2f){0.f, 0.f};
        }

        __syncthreads();
        buf ^= 1;
    }

    {
        v2f bvp = *(const v2f*)(bias + cot * 32 + cog2);
        const int co0 = cot * 32 + cog2;
#pragma unroll
        for (int o = 0; o < 2; ++o) {
            const int oy = 2 * by + o;
            v2f T0 = pk_add2(TOT[o][0], bvp);
            v2f T1 = pk_add2(TOT[o][1], bvp);
            float r00 = fmaxf(T0.x, 0.f), r01 = fmaxf(T1.x, 0.f);
            float r10 = fmaxf(T0.y, 0.f), r11 = fmaxf(T1.y, 0.f);
            v2f o0; o0.x = r00; o0.y = r01;
            v2f o1; o1.x = r10; o1.y = r11;
            size_t base = (size_t)img * 2097152 + (size_t)oy * 128
                          + xbase + 2 * xg;
            *(v2f*)&out[base + (size_t)co0 * 16384] = o0;
            *(v2f*)&out[base + (size_t)(co0 + 1) * 16384] = o1;
        }
    }
}

// ---------------- conv3: 128->128, 4x4, s2, p1, 128->64. K=2048.
// 2 oy per THREAD; 32 chunks of 4 ci; chunk-pair leaves; two 8-leaf halves.
__global__ __launch_bounds__(256) void conv3_kernel(
    const float* __restrict__ in, const float* __restrict__ wT,
    const float* __restrict__ bias, float* __restrict__ out) {
#pragma clang fp contract(off)
    __shared__ __align__(16) float Wl[2][4][16][32];
    __shared__ __align__(16) float Il[2][4][6][68];
    const int tid = threadIdx.x;
    const int xg = tid & 15, cog = tid >> 4;
    const int cog2 = cog * 2;
    const int xt = blockIdx.x & 1, cot = blockIdx.x >> 1;
    const int by = blockIdx.y;
    const int img = blockIdx.z;
    const int xbase = 32 * xt;
    const float* inp = in + (size_t)img * 2097152;
    const int gx0 = 2 * xbase - 1;
    const int iy0 = 4 * by - 1;
    const int lane = tid & 63, wid = tid >> 6;

    int ldsoff[7]; int goff[7]; bool gok[7];
#pragma unroll
    for (int i = 0; i < 7; ++i) {
        int e = tid + i * 256;
        int cl = e / 396;
        int rem = e - cl * 396;
        int row = rem / 66, col = rem - row * 66;
        int iy = iy0 + row, gx = gx0 + col;
        gok[i] = (e < 1584) && ((unsigned)iy < 128u) && ((unsigned)gx < 128u);
        ldsoff[i] = (cl * 6 + row) * 68 + col;
        goff[i] = cl * 16384 + iy * 128 + gx;
    }
    const float* wbase = wT + cot * 32;

    float rIl[7];
    auto LOAD_IL = [&](int c) {
        const float* p = inp + (size_t)c * 65536;  // 4ci * 16384
#pragma unroll
        for (int i = 0; i < 7; ++i)
            rIl[i] = gok[i] ? p[goff[i]] : 0.f;
    };
    auto WRITE_IL = [&](float* dst) {
#pragma unroll
        for (int i = 0; i < 6; ++i) dst[ldsoff[i]] = rIl[i];
        if (tid < 48) dst[ldsoff[6]] = rIl[6];
    };

    v2f acc[2][8][2];
    v2f tA[2][2], tB[2][2], Q0[2][2], AB0[2][2], TOT[2][2];
#pragma unroll
    for (int o = 0; o < 2; ++o)
#pragma unroll
        for (int j = 0; j < 8; ++j)
#pragma unroll
            for (int xi = 0; xi < 2; ++xi) acc[o][j][xi] = (v2f){0.f, 0.f};

    stage_w4(wbase, &Wl[0][0][0][0], wid, lane);
    LOAD_IL(0);
    WRITE_IL(&Il[0][0][0][0]);
    LOAD_IL(1);
    __syncthreads();

    int buf = 0;
    for (int c = 0; c < 32; ++c) {
        const float* IlC = &Il[buf][0][0][0];
        const float* WlC = &Wl[buf][0][0][0];
        if (c < 31) {
            WRITE_IL(&Il[buf ^ 1][0][0][0]);
            stage_w4(wbase + (size_t)(c + 1) * 8192, &Wl[buf ^ 1][0][0][0],
                     wid, lane);
        }
        if (c < 30) LOAD_IL(c + 2);

        for (int cl = 0; cl < 4; ++cl) {
            v2f rpa[2][3], rpb[2][3], wp[8];
#pragma unroll
            for (int ky = 0; ky < 2; ++ky) {
                const float* r0 = IlC + (cl * 6 + ky) * 68 + 4 * xg;
                rpa[ky][0] = *(const v2f*)(r0);
                rpa[ky][1] = *(const v2f*)(r0 + 2);
                rpa[ky][2] = *(const v2f*)(r0 + 4);
                const float* r2 = IlC + (cl * 6 + 2 + ky) * 68 + 4 * xg;
                rpb[ky][0] = *(const v2f*)(r2);
                rpb[ky][1] = *(const v2f*)(r2 + 2);
                rpb[ky][2] = *(const v2f*)(r2 + 4);
            }
#pragma unroll
            for (int f = 0; f < 8; ++f)
                wp[f] = *(const v2f*)(WlC + (cl * 16 + f) * 32 + cog2);
            MACGRP(acc[0], rpa, wp);
            MACGRP(acc[1], rpb, wp);
#pragma unroll
            for (int f = 0; f < 8; ++f)
                wp[f] = *(const v2f*)(WlC + (cl * 16 + 8 + f) * 32 + cog2);
#pragma unroll
            for (int ky = 0; ky < 2; ++ky) {
                const float* r4 = IlC + (cl * 6 + 4 + ky) * 68 + 4 * xg;
                rpa[ky][0] = *(const v2f*)(r4);
                rpa[ky][1] = *(const v2f*)(r4 + 2);
                rpa[ky][2] = *(const v2f*)(r4 + 4);
            }
            MACGRP(acc[0], rpb, wp);
            MACGRP(acc[1], rpa, wp);
        }

        if (c & 1) {
            const int L = c >> 1;          // 0..15
            const int L8 = L & 7, half = L >> 3;
#pragma unroll
            for (int o = 0; o < 2; ++o)
#pragma unroll
                for (int xi = 0; xi < 2; ++xi) {
                    v2f t01 = pk_add2(acc[o][0][xi], acc[o][1][xi]);
                    v2f t23 = pk_add2(acc[o][2][xi], acc[o][3][xi]);
                    v2f t45 = pk_add2(acc[o][4][xi], acc[o][5][xi]);
                    v2f t67 = pk_add2(acc[o][6][xi], acc[o][7][xi]);
                    v2f lf = pk_add2(pk_add2(t01, t23), pk_add2(t45, t67));
                    const int m = L8 & 3;
                    if (m == 0) tA[o][xi] = lf;
                    else if (m == 1) tA[o][xi] = pk_add2(tA[o][xi], lf);
                    else if (m == 2) tB[o][xi] = lf;
                    else {
                        tB[o][xi] = pk_add2(tB[o][xi], lf);
                        v2f q = pk_add2(tA[o][xi], tB[o][xi]);
                        if (L8 == 3) Q0[o][xi] = q;
                        else {
                            v2f h = pk_add2(Q0[o][xi], q);  // p(1024)
                            if (half == 0) AB0[o][xi] = h;
                            else TOT[o][xi] = pk_add2(AB0[o][xi], h); // p(2048)
                        }
                    }
                }
#pragma unroll
            for (int o = 0; o < 2; ++o)
#pragma unroll
                for (int j = 0; j < 8; ++j)
#pragma unroll
                    for (int xi = 0; xi < 2; ++xi)
                        acc[o][j][xi] = (v2f){0.f, 0.f};
        }

        __syncthreads();
        buf ^= 1;
    }

    {
        v2f bvp = *(const v2f*)(bias + cot * 32 + cog2);
        const int co0 = cot * 32 + cog2;
#pragma unroll
        for (int o = 0; o < 2; ++o) {
            const int oy = 2 * by + o;
            v2f T0 = pk_add2(TOT[o][0], bvp);
            v2f T1 = pk_add2(TOT[o][1], bvp);
            float r00 = fmaxf(T0.x, 0.f), r01 = fmaxf(T1.x, 0.f);
            float r10 = fmaxf(T0.y, 0.f), r11 = fmaxf(T1.y, 0.f);
            v2f o0; o0.x = r00; o0.y = r01;
            v2f o1; o1.x = r10; o1.y = r11;
            size_t base = (size_t)img * 524288 + (size_t)oy * 64
                          + xbase + 2 * xg;
            *(v2f*)&out[base + (size_t)co0 * 4096] = o0;
            *(v2f*)&out[base + (size_t)(co0 + 1) * 4096] = o1;
        }
    }
}

// ---------------- conv4: 128->4, 3x3, s1, p1 (unchanged from R12)
__global__ __launch_bounds__(256) void conv4_kernel(
    const float* __restrict__ h3, const float* __restrict__ w4,
    const float* __restrict__ b4, float* __restrict__ z, int b0) {
#pragma clang fp contract(off)
    __shared__ __align__(16) float Il3[8][3][66];
    __shared__ __align__(16) float w4l[4608];
    const int tid = threadIdx.x;
    const int wl = tid & 63, co = tid >> 6;
    const int h = blockIdx.x, bl = blockIdx.y;
    const float* inp = h3 + (size_t)bl * 524288;

    for (int it = 0; it < 18; ++it) {
        int e = tid + it * 256;
        if (e < 4608) w4l[e] = w4[e];
    }

    float ls[16];
    for (int L = 0; L < 16; ++L) {
        __syncthreads();
        for (int it = 0; it < 7; ++it) {
            int e = tid + it * 256;
            if (e < 1584) {
                int cil = e / 198;
                int rem = e - cil * 198;
                int ky = rem / 66, col = rem - ky * 66;
                int iy = h - 1 + ky, gx = col - 1;
                bool ok = ((unsigned)iy < 64u) && ((unsigned)gx < 64u);
                Il3[cil][ky][col] =
                    ok ? inp[(size_t)(8 * L + cil) * 4096 + iy * 64 + gx] : 0.f;
            }
        }
        __syncthreads();

        float r[8];
#pragma unroll
        for (int j = 0; j < 8; ++j) r[j] = 0.f;
#pragma unroll
        for (int i = 0; i < 9; ++i) {
#pragma unroll
            for (int j = 0; j < 8; ++j) {
                int kk = 8 * i + j;
                int cil = kk / 9, f = kk - 9 * cil;
                int ky = f / 3, kx = f - 3 * ky;
                float p = Il3[cil][ky][wl + kx] *
                          w4l[co * 1152 + (8 * L + cil) * 9 + f];
                r[j] = r[j] + p;
            }
        }
        float t01 = r[0] + r[1], t23 = r[2] + r[3];
        float t45 = r[4] + r[5], t67 = r[6] + r[7];
        ls[L] = (t01 + t23) + (t45 + t67);
    }

    float a01 = ls[0] + ls[1],  a23 = ls[2] + ls[3];
    float a45 = ls[4] + ls[5],  a67 = ls[6] + ls[7];
    float A = (a01 + a23) + (a45 + a67);
    float c01 = ls[8] + ls[9],  c23 = ls[10] + ls[11];
    float c45 = ls[12] + ls[13], c67 = ls[14] + ls[15];
    float B = (c01 + c23) + (c45 + c67);
    float tot = A + B;

    z[(size_t)(b0 + bl) * 16384 + (size_t)co * 4096 + (size_t)h * 64 + wl] =
        tot + b4[co];
}

// ---------------- VQ (unchanged from R12)
__global__ __launch_bounds__(256) void vq_kernel(
    const float* __restrict__ z, const float* __restrict__ emb,
    float* __restrict__ zq_out, float* __restrict__ idx_out,
    float* __restrict__ loss_out) {
#pragma clang fp contract(off)
    __shared__ float4 el[512];
    __shared__ float t3s[512];
    const int tid = threadIdx.x;
#pragma unroll
    for (int i = 0; i < 2; ++i) {
        int e = tid + i * 256;
        float4 v = ((const float4*)emb)[e];
        el[e] = v;
        float q0 = v.x * v.x, q1 = v.y * v.y, q2 = v.z * v.z, q3 = v.w * v.w;
        t3s[e] = ((q0 + q1) + q2) + q3;
    }
    __syncthreads();

    const int r = blockIdx.x * 256 + tid;
    float4 v = ((const float4*)z)[r];
    float q0 = v.x * v.x, q1 = v.y * v.y, q2 = v.z * v.z, q3 = v.w * v.w;
    float t1 = ((q0 + q1) + q2) + q3;

    float best = __builtin_inff();
    int bi = 0;
    for (int jj = 0; jj < 512; ++jj) {
        float4 e = el[jj];
        float t2 = fmaf(v.x, e.x, 0.f);
        t2 = fmaf(v.y, e.y, t2);
        t2 = fmaf(v.z, e.z, t2);
        t2 = fmaf(v.w, e.w, t2);
        float two_t2 = 2.f * t2;
        float d = (t1 - two_t2) + t3s[jj];
        if (d < best) { best = d; bi = jj; }
    }
    float4 q = el[bi];
    ((float4*)zq_out)[r] = q;
    idx_out[r] = (float)bi;

    double dx = (double)q.x - v.x, dy = (double)q.y - v.y;
    double dz2 = (double)q.z - v.z, dw = (double)q.w - v.w;
    double part = dx * dx + dy * dy + dz2 * dz2 + dw * dw;
#pragma unroll
    for (int off = 32; off > 0; off >>= 1) part += __shfl_down(part, off, 64);
    __shared__ double ps[4];
    if ((tid & 63) == 0) ps[tid >> 6] = part;
    __syncthreads();
    if (tid == 0) {
        double s = ps[0] + ps[1] + ps[2] + ps[3];
        atomicAdd(loss_out, (float)(s * (1.25 / 262144.0)));
    }
}

// ---------------------------------------------------------------------------
extern "C" void kernel_launch(void* const* d_in, const int* in_sizes, int n_in,
                              void* d_out, int out_size, void* d_ws, size_t ws_size,
                              hipStream_t stream) {
    const float* x   = (const float*)d_in[0];
    const float* w1  = (const float*)d_in[1];
    const float* b1  = (const float*)d_in[2];
    const float* w2  = (const float*)d_in[3];
    const float* b2  = (const float*)d_in[4];
    const float* w3  = (const float*)d_in[5];
    const float* b3  = (const float*)d_in[6];
    const float* w4  = (const float*)d_in[7];
    const float* b4  = (const float*)d_in[8];
    const float* emb = (const float*)d_in[9];
    float* out = (float*)d_out;

    float* ws = (float*)d_ws;
    // layout (floats): zb[262144] | wT2[131072] | wT3[262144]
    //                 | h1c[CH*4194304] | h2c[CH*2097152] | h3c[CH*524288]
    int CH = 4;
    while (CH > 1 &&
           ((size_t)655360u + (size_t)CH * 6815744u) * 4ull > ws_size)
        CH >>= 1;
    float* zb  = ws;
    float* wT2 = ws + 262144;
    float* wT3 = wT2 + 131072;
    float* h1c = wT3 + 262144;
    float* h2c = h1c + (size_t)CH * 4194304;
    float* h3c = h2c + (size_t)CH * 2097152;

    wt_kernel<<<1536, 256, 0, stream>>>(w2, w3, wT2, wT3);

    for (int b0 = 0; b0 < 16; b0 += CH) {
        conv1_kernel<<<dim3(4, 16, CH), 256, 0, stream>>>(
            x + (size_t)b0 * 262144, w1, b1, h1c);
        conv2_kernel<<<dim3(16, 64, CH), 256, 0, stream>>>(h1c, wT2, b2, h2c);
        conv3_kernel<<<dim3(8, 32, CH), 256, 0, stream>>>(h2c, wT3, b3, h3c);
        conv4_kernel<<<dim3(64, CH), 256, 0, stream>>>(h3c, w4, b4, zb, b0);
    }

    hipMemsetAsync(out + 262144, 0, sizeof(float), stream);  // loss accumulator
    vq_kernel<<<256, 256, 0, stream>>>(zb, emb, out, out + 262144 + 1, out + 262144);
}